// Round 1
// baseline (7141.559 us; speedup 1.0000x reference)
//
#include <hip/hip_runtime.h>
#include <stdint.h>

// ---------------------------------------------------------------------------
// CustomGRU: B=64, S=512, I=256, H=1024
//  xg = x @ (Wi@Wgx) + (bi@Wgx + bg)   (one fused GEMM, 3 gates concat, N=3072)
//  scan: z = sig(xz + h@Wzh); r = sig(xr + h@Wrh);
//        n = tanh(xn + (r*h)@Wnh);  h' = (1-z)n + z h      [(r*h)@W per py prec]
//
// R2 (this round): sync-fabric diet for the recurrence.
//  - COMPACT FLAGS: one int per (bg,ng), 64 ints = 2 LLC lines per domain.
//    Old layout (128B stride) made every poll touch 64 lines => ~5 TB/s of
//    poll traffic congesting the LLC. Now a poll touches 2 lines.
//  - SUBSET WAITS: wave w only reads k in [w*256,(w+1)*256) => it waits only
//    on its 16 producers (ng = w*16..w*16+15). Union over 4 waves = all 64
//    peers, and the per-phase red-barrier joins waves, so every buffer
//    overwrite still happens-after all peers' reads (anti-deps safe).
//  - 2 barriers/step instead of 6: producer wave packs bf16 pairs in-wave via
//    shfl_xor, drains its own stores (wave-local s_waitcnt vmcnt(0)), sets the
//    flag itself; consumers spin per-wave (no release barrier).
//  - out[]/hfin HBM stores issued AFTER the flag (were adding ~900cy of HBM
//    store-ack to the critical path via the pre-barrier vmcnt drain).
//  - xg pre-activations for step t+1 prefetched into registers during step t.
// ---------------------------------------------------------------------------

using f32x4  = __attribute__((ext_vector_type(4))) float;
using bf16x8 = __attribute__((ext_vector_type(8))) __bf16;
using u16x8  = __attribute__((ext_vector_type(8))) unsigned short;
using u16x4  = __attribute__((ext_vector_type(4))) unsigned short;
typedef unsigned long long ull;

__device__ __forceinline__ unsigned short f2bf(float x) {
  union { float f; uint32_t u; } v; v.f = x;
  uint32_t u = v.u;
  return (unsigned short)((u + 0x7fffu + ((u >> 16) & 1u)) >> 16);  // RNE
}
__device__ __forceinline__ float bf2f(unsigned short u) {
  union { uint32_t u; float f; } v; v.u = ((uint32_t)u) << 16;
  return v.f;
}
__device__ __forceinline__ bf16x8 ld_b8(const unsigned short* p) {
  return *(const bf16x8*)p;
}
__device__ __forceinline__ float xg_get(const float* p) { return *p; }
__device__ __forceinline__ float xg_get(const unsigned short* p) { return bf2f(*p); }
__device__ __forceinline__ void  xg_put(float* p, float v) { *p = v; }
__device__ __forceinline__ void  xg_put(unsigned short* p, float v) { *p = f2bf(v); }
__device__ __forceinline__ float sigm(float x) { return 1.f / (1.f + __expf(-x)); }
__device__ __forceinline__ float tanh_(float x) { float e = __expf(2.f * x); return 1.f - 2.f / (e + 1.f); }
__device__ __forceinline__ uint32_t pack2(float lo, float hi) {
  return (uint32_t)f2bf(lo) | ((uint32_t)f2bf(hi) << 16);
}

__device__ __forceinline__ ull ld_agent(const ull* p) {
  return __hip_atomic_load(p, __ATOMIC_RELAXED, __HIP_MEMORY_SCOPE_AGENT);
}
__device__ __forceinline__ void st_agent(uint32_t* p, uint32_t v) {
  __hip_atomic_store(p, v, __ATOMIC_RELAXED, __HIP_MEMORY_SCOPE_AGENT);
}
__device__ __forceinline__ int ld_flag(const int* p) {
  return __hip_atomic_load(p, __ATOMIC_RELAXED, __HIP_MEMORY_SCOPE_AGENT);
}
__device__ __forceinline__ void st_flag(int* p, int v) {
  __hip_atomic_store(p, v, __ATOMIC_RELAXED, __HIP_MEMORY_SCOPE_AGENT);
}
// whole-wave spin on this wave's 16-producer subset (quads duplicate => 2 lines)
__device__ __forceinline__ void spin_wait(const int* fp, int target) {
  while (true) {
    const int v = ld_flag(fp);
    if (__all(v >= target)) break;
    __builtin_amdgcn_s_sleep(1);
  }
  __atomic_signal_fence(__ATOMIC_ACQUIRE);
}

// ---------------------------------------------------------------------------
// K1: WcT[n(3072)][i(256)] (bf16) = (Wi @ Wgx)^T.  1.6 GFLOP.
// ---------------------------------------------------------------------------
__global__ __launch_bounds__(256) void wc_kernel(
    const float* __restrict__ Wi, const float* __restrict__ Wz,
    const float* __restrict__ Wr, const float* __restrict__ Wn,
    unsigned short* __restrict__ WcT)
{
  const int ntile = blockIdx.x >> 4, itile = blockIdx.x & 15;  // 48 x 16
  const int n_g = ntile * 64 + (threadIdx.x & 63);             // 0..3071
  const int g = n_g >> 10, n = n_g & 1023;
  const float* Wg = (g == 0) ? Wz : (g == 1) ? Wr : Wn;        // rows [0,H) = W*_x
  const int i0 = itile * 16 + ((threadIdx.x >> 6) << 2);
  float a0 = 0.f, a1 = 0.f, a2 = 0.f, a3 = 0.f;
  for (int k = 0; k < 1024; ++k) {
    const float wv = Wg[(size_t)k * 1024 + n];
    a0 += Wi[(i0 + 0) * 1024 + k] * wv;
    a1 += Wi[(i0 + 1) * 1024 + k] * wv;
    a2 += Wi[(i0 + 2) * 1024 + k] * wv;
    a3 += Wi[(i0 + 3) * 1024 + k] * wv;
  }
  WcT[(size_t)n_g * 256 + i0 + 0] = f2bf(a0);
  WcT[(size_t)n_g * 256 + i0 + 1] = f2bf(a1);
  WcT[(size_t)n_g * 256 + i0 + 2] = f2bf(a2);
  WcT[(size_t)n_g * 256 + i0 + 3] = f2bf(a3);
}

// ---------------------------------------------------------------------------
// K2: bc[n(3072)] = bi @ Wgx + bg  (fp32)
// ---------------------------------------------------------------------------
__global__ __launch_bounds__(256) void bc_kernel(
    const float* __restrict__ bi, const float* __restrict__ Wz,
    const float* __restrict__ Wr, const float* __restrict__ Wn,
    const float* __restrict__ bz, const float* __restrict__ br,
    const float* __restrict__ bn, float* __restrict__ bc)
{
  const int n_g = blockIdx.x * 256 + threadIdx.x;
  const int g = n_g >> 10, n = n_g & 1023;
  const float* Wg = (g == 0) ? Wz : (g == 1) ? Wr : Wn;
  const float* bg = (g == 0) ? bz : (g == 1) ? br : bn;
  float acc = bg[n];
  for (int k = 0; k < 1024; ++k) acc += bi[k] * Wg[(size_t)k * 1024 + n];
  bc[n_g] = acc;
}

// ---------------------------------------------------------------------------
// K3: WhhT[g][col(1024)][k(1024)] (bf16) = Wg[H + k][col]  (tile transpose)
// ---------------------------------------------------------------------------
__global__ __launch_bounds__(256) void whT_kernel(
    const float* __restrict__ Wz, const float* __restrict__ Wr,
    const float* __restrict__ Wn, unsigned short* __restrict__ WhhT)
{
  __shared__ float tile[64][65];
  const int g = blockIdx.x >> 8;
  const int rem = blockIdx.x & 255;
  const int kt = rem >> 4, ct = rem & 15;
  const float* Wg = (g == 0) ? Wz : (g == 1) ? Wr : Wn;
  const int tx = threadIdx.x & 63, ty = threadIdx.x >> 6;
  #pragma unroll
  for (int j = 0; j < 16; ++j) {
    const int k = kt * 64 + ty + j * 4;
    tile[ty + j * 4][tx] = Wg[(size_t)(1024 + k) * 1024 + ct * 64 + tx];
  }
  __syncthreads();
  #pragma unroll
  for (int j = 0; j < 16; ++j) {
    const int c = ct * 64 + ty + j * 4;
    WhhT[((size_t)g * 1024 + c) * 1024 + kt * 64 + tx] = f2bf(tile[tx][ty + j * 4]);
  }
}

// ---------------------------------------------------------------------------
// K4: gates GEMM  xg[s][b][3072] = x @ Wc + bc.  M=32768, N=3072, K=256.
// ---------------------------------------------------------------------------
template <typename XT>
__global__ __launch_bounds__(256) void gates_kernel(
    const float* __restrict__ x, const unsigned short* __restrict__ WcT,
    const float* __restrict__ bc, XT* __restrict__ xg)
{
  __shared__ __align__(16) unsigned short As[128 * 72];
  __shared__ __align__(16) unsigned short Bs[128 * 72];
  const int t = threadIdx.x;
  const int lane = t & 63, wid = t >> 6;
  const int wm = wid >> 1, wn = wid & 1;
  const int ml = lane & 15, quad = lane >> 4;
  const int mb = blockIdx.x / 24, nb = blockIdx.x % 24;
  const int m0 = mb * 128, n0 = nb * 128;
  f32x4 acc[4][4];
  #pragma unroll
  for (int i = 0; i < 4; ++i)
    #pragma unroll
    for (int j = 0; j < 4; ++j) acc[i][j] = (f32x4){0.f, 0.f, 0.f, 0.f};

  for (int kc = 0; kc < 4; ++kc) {
    {
      const int row = t >> 4, c4 = t & 15;
      #pragma unroll
      for (int i = 0; i < 8; ++i) {
        const f32x4 v = *(const f32x4*)(x + (size_t)(m0 + row + i * 16) * 256 + kc * 64 + c4 * 4);
        u16x4 b4 = { f2bf(v[0]), f2bf(v[1]), f2bf(v[2]), f2bf(v[3]) };
        *(u16x4*)&As[(row + i * 16) * 72 + c4 * 4] = b4;
      }
      const int rowB = t >> 3, ch = t & 7;
      #pragma unroll
      for (int i = 0; i < 4; ++i) {
        const u16x8 v = *(const u16x8*)(WcT + (size_t)(n0 + rowB + i * 32) * 256 + kc * 64 + ch * 8);
        *(u16x8*)&Bs[(rowB + i * 32) * 72 + ch * 8] = v;
      }
    }
    __syncthreads();
    #pragma unroll
    for (int kt = 0; kt < 2; ++kt) {
      bf16x8 a[4], b[4];
      #pragma unroll
      for (int mt = 0; mt < 4; ++mt) a[mt] = ld_b8(&As[(wm * 64 + mt * 16 + ml) * 72 + kt * 32 + quad * 8]);
      #pragma unroll
      for (int nt = 0; nt < 4; ++nt) b[nt] = ld_b8(&Bs[(wn * 64 + nt * 16 + ml) * 72 + kt * 32 + quad * 8]);
      #pragma unroll
      for (int mt = 0; mt < 4; ++mt)
        #pragma unroll
        for (int nt = 0; nt < 4; ++nt)
          acc[mt][nt] = __builtin_amdgcn_mfma_f32_16x16x32_bf16(a[mt], b[nt], acc[mt][nt], 0, 0, 0);
    }
    __syncthreads();
  }
  #pragma unroll
  for (int nt = 0; nt < 4; ++nt) {
    const int n = n0 + wn * 64 + nt * 16 + ml;
    const float bcv = bc[n];
    #pragma unroll
    for (int mt = 0; mt < 4; ++mt) {
      #pragma unroll
      for (int r = 0; r < 4; ++r) {
        const int m = m0 + wm * 64 + mt * 16 + quad * 4 + r;
        const int b = m >> 9, s = m & 511;
        xg_put(&xg[((size_t)s * 64 + b) * 3072 + n], acc[mt][nt][r] + bcv);
      }
    }
  }
}

// ---------------------------------------------------------------------------
// K5: persistent recurrence. 256 WGs = 4 batch-groups(16 b) x 64 col-groups(16 h).
// Flag values monotone: rh(t) ready => 2t+1 (set by wid1); h(t+1) ready => 2t+2
// (set by wid0). Anti-dep safety: wave w waits on producers w*16..w*16+15 only;
// union over 4 waves = all 64 peers, and the red-barrier joins waves before any
// buffer is overwritten, so "all peers emitted flag" holds at every overwrite.
// ---------------------------------------------------------------------------
template <typename XT>
__global__ __launch_bounds__(256, 1) void recur_kernel(
    const unsigned short* __restrict__ WhhT, const XT* __restrict__ xg,
    unsigned short* __restrict__ hbuf, unsigned short* __restrict__ rhbuf,
    int* __restrict__ flags, float* __restrict__ out, float* __restrict__ hfin)
{
  __shared__ __align__(16) float red[12 * 256];  // A: buf 0..7, B: buf 8..11
  __shared__ float zbuf[256];
  __shared__ float hprev[256];  // exact fp32 h slice of this WG

  const int tid  = threadIdx.x;
  const int lane = tid & 63;
  const int wid  = tid >> 6;
  const int ml   = lane & 15;
  const int quad = lane >> 4;
  const int bg   = blockIdx.x & 3;   // batch group 0..3 (domain)
  const int ng   = blockIdx.x >> 2;  // col group 0..63

  // ---- weights -> registers: wave `wid` owns kt = wid*8 .. wid*8+7 ----
  bf16x8 wz_r[8], wr_r[8], wn_r[8];
  #pragma unroll
  for (int k8 = 0; k8 < 8; ++k8) {
    const int kt = wid * 8 + k8;
    const size_t base = (size_t)(ng * 16 + ml) * 1024 + kt * 32 + quad * 8;
    wz_r[k8] = ld_b8(WhhT + base);
    wr_r[k8] = ld_b8(WhhT + (1u << 20) + base);
    wn_r[k8] = ld_b8(WhhT + (2u << 20) + base);
  }
  hprev[tid] = 0.f;

  // compact flags: flags[bg*64 + ng], one int each (domain = 256B = 2 lines)
  int* __restrict__ myflag = flags + bg * 64 + ng;
  const int* __restrict__ peerflag = flags + bg * 64 + wid * 16 + ml;

  const ull*  hb_base = (const ull*)hbuf;        // [parity(16384)][b(256 ull rows...)]
  const ull*  rb_base = (const ull*)rhbuf;
  uint32_t*   hb_w    = (uint32_t*)hbuf;
  uint32_t*   rb_w    = (uint32_t*)rhbuf;

  // xg pre-activation registers (double-buffered across steps)
  const size_t xrow = (size_t)(bg * 16 + quad * 4) * 3072 + ng * 16 + ml;
  float xz_c[4] = {0,0,0,0}, xn_c[4] = {0,0,0,0}, xr_c[4] = {0,0,0,0};
  float xz_n[4] = {0,0,0,0}, xn_n[4] = {0,0,0,0}, xr_n[4] = {0,0,0,0};
  if (wid == 0) {
    #pragma unroll
    for (int r = 0; r < 4; ++r) {
      xz_c[r] = xg_get(&xg[xrow + (size_t)r * 3072]);
      xn_c[r] = xg_get(&xg[xrow + (size_t)r * 3072 + 2048]);
    }
  } else if (wid == 1) {
    #pragma unroll
    for (int r = 0; r < 4; ++r)
      xr_c[r] = xg_get(&xg[xrow + (size_t)r * 3072 + 1024]);
  }
  __syncthreads();

  for (int t = 0; t < 512; ++t) {
    // ================= phase A: z, r =================
    bf16x8 hv[8];
    {
      const ull* hb = hb_base + (size_t)(t & 1) * 16384;
      #pragma unroll
      for (int k8 = 0; k8 < 8; ++k8) {
        const int kt = wid * 8 + k8;
        const size_t idx = (size_t)(bg * 16 + ml) * 256 + kt * 8 + quad * 2;
        union { ull q[2]; bf16x8 v; } u;
        u.q[0] = ld_agent(hb + idx);
        u.q[1] = ld_agent(hb + idx + 1);
        hv[k8] = u.v;
      }
    }
    f32x4 accZ = {0.f, 0.f, 0.f, 0.f}, accR = {0.f, 0.f, 0.f, 0.f};
    #pragma unroll
    for (int k8 = 0; k8 < 8; ++k8) {
      accZ = __builtin_amdgcn_mfma_f32_16x16x32_bf16(hv[k8], wz_r[k8], accZ, 0, 0, 0);
      accR = __builtin_amdgcn_mfma_f32_16x16x32_bf16(hv[k8], wr_r[k8], accR, 0, 0, 0);
    }
    *(f32x4*)&red[(wid * 2 + 0) * 256 + lane * 4] = accZ;
    *(f32x4*)&red[(wid * 2 + 1) * 256 + lane * 4] = accR;
    __syncthreads();   // barrier 1 of 2

    if (wid == 0) {
      f32x4 s = {0.f, 0.f, 0.f, 0.f};
      #pragma unroll
      for (int w = 0; w < 4; ++w) s += *(const f32x4*)&red[(w * 2) * 256 + lane * 4];
      #pragma unroll
      for (int r = 0; r < 4; ++r)
        zbuf[(quad * 4 + r) * 16 + ml] = sigm(s[r] + xz_c[r]);
      if (t < 511) {   // prefetch z/n pre-acts for t+1 (hidden under spin)
        const XT* xp = xg + (size_t)(t + 1) * 196608 + xrow;
        #pragma unroll
        for (int r = 0; r < 4; ++r) {
          xz_n[r] = xg_get(xp + (size_t)r * 3072);
          xn_n[r] = xg_get(xp + (size_t)r * 3072 + 2048);
        }
      }
    } else if (wid == 1) {
      f32x4 s = {0.f, 0.f, 0.f, 0.f};
      #pragma unroll
      for (int w = 0; w < 4; ++w) s += *(const f32x4*)&red[(w * 2 + 1) * 256 + lane * 4];
      const float rh0 = sigm(s[0] + xr_c[0]) * hprev[(quad * 4 + 0) * 16 + ml];
      const float rh1 = sigm(s[1] + xr_c[1]) * hprev[(quad * 4 + 1) * 16 + ml];
      const float rh2 = sigm(s[2] + xr_c[2]) * hprev[(quad * 4 + 2) * 16 + ml];
      const float rh3 = sigm(s[3] + xr_c[3]) * hprev[(quad * 4 + 3) * 16 + ml];
      // in-wave bf16 pair pack: cols (2p,2p+1) live in lanes ml=2p,2p+1
      const int odd = ml & 1;
      const float o0 = __shfl_xor(rh0, 1), o1 = __shfl_xor(rh1, 1);
      const float o2 = __shfl_xor(rh2, 1), o3 = __shfl_xor(rh3, 1);
      const uint32_t w0 = pack2(odd ? o0 : rh0, odd ? rh0 : o0);
      const uint32_t w1 = pack2(odd ? o1 : rh1, odd ? rh1 : o1);
      const uint32_t w2 = pack2(odd ? o2 : rh2, odd ? rh2 : o2);
      const uint32_t w3 = pack2(odd ? o3 : rh3, odd ? rh3 : o3);
      const uint32_t wa = odd ? w2 : w0;     // even lanes store rows r0,r1
      const uint32_t wb = odd ? w3 : w1;     // odd lanes store rows r2,r3
      const int row0 = quad * 4 + odd * 2;
      const size_t sa = (size_t)(bg * 16 + row0) * 512 + ng * 8 + (ml >> 1);
      st_agent(rb_w + sa, wa);
      st_agent(rb_w + sa + 512, wb);
      asm volatile("s_waitcnt vmcnt(0)" ::: "memory");  // wave-local drain
      if (lane == 0) st_flag(myflag, 2 * t + 1);
      asm volatile("" ::: "memory");
      if (t < 511) {   // prefetch r pre-acts for t+1 (after drain, not in it)
        const XT* xp = xg + (size_t)(t + 1) * 196608 + xrow + 1024;
        #pragma unroll
        for (int r = 0; r < 4; ++r) xr_n[r] = xg_get(xp + (size_t)r * 3072);
      }
    }
    spin_wait(peerflag, 2 * t + 1);   // each wave waits only its 16 producers

    // ================= phase B: n, h' =================
    bf16x8 rv[8];
    #pragma unroll
    for (int k8 = 0; k8 < 8; ++k8) {
      const int kt = wid * 8 + k8;
      const size_t idx = (size_t)(bg * 16 + ml) * 256 + kt * 8 + quad * 2;
      union { ull q[2]; bf16x8 v; } u;
      u.q[0] = ld_agent(rb_base + idx);
      u.q[1] = ld_agent(rb_base + idx + 1);
      rv[k8] = u.v;
    }
    f32x4 accN = {0.f, 0.f, 0.f, 0.f};
    #pragma unroll
    for (int k8 = 0; k8 < 8; ++k8)
      accN = __builtin_amdgcn_mfma_f32_16x16x32_bf16(rv[k8], wn_r[k8], accN, 0, 0, 0);
    *(f32x4*)&red[(8 + wid) * 256 + lane * 4] = accN;
    __syncthreads();   // barrier 2 of 2

    if (wid == 0) {
      f32x4 s = {0.f, 0.f, 0.f, 0.f};
      #pragma unroll
      for (int w = 0; w < 4; ++w) s += *(const f32x4*)&red[(8 + w) * 256 + lane * 4];
      float hn[4];
      #pragma unroll
      for (int r = 0; r < 4; ++r) {
        const int bl = quad * 4 + r;
        const float nv  = tanh_(s[r] + xn_c[r]);
        const float z   = zbuf[bl * 16 + ml];
        const float hv0 = hprev[bl * 16 + ml];
        hn[r] = (1.f - z) * nv + z * hv0;
        hprev[bl * 16 + ml] = hn[r];
      }
      const int odd = ml & 1;
      const float o0 = __shfl_xor(hn[0], 1), o1 = __shfl_xor(hn[1], 1);
      const float o2 = __shfl_xor(hn[2], 1), o3 = __shfl_xor(hn[3], 1);
      const uint32_t w0 = pack2(odd ? o0 : hn[0], odd ? hn[0] : o0);
      const uint32_t w1 = pack2(odd ? o1 : hn[1], odd ? hn[1] : o1);
      const uint32_t w2 = pack2(odd ? o2 : hn[2], odd ? hn[2] : o2);
      const uint32_t w3 = pack2(odd ? o3 : hn[3], odd ? hn[3] : o3);
      const uint32_t wa = odd ? w2 : w0;
      const uint32_t wb = odd ? w3 : w1;
      const int row0 = quad * 4 + odd * 2;
      const size_t sa = (size_t)((t + 1) & 1) * 32768 +
                        (size_t)(bg * 16 + row0) * 512 + ng * 8 + (ml >> 1);
      st_agent(hb_w + sa, wa);
      st_agent(hb_w + sa + 512, wb);
      asm volatile("s_waitcnt vmcnt(0)" ::: "memory");  // wave-local drain
      if (lane == 0) st_flag(myflag, 2 * t + 2);
      asm volatile("" ::: "memory");
      // out/hfin stores AFTER the flag: off the signalling critical path,
      // drained by next step's wave-local vmcnt(0) (fully hidden).
      const size_t ob = ((size_t)(bg * 16 + quad * 4) * 512 + t) * 1024 + ng * 16 + ml;
      __builtin_nontemporal_store(hn[0], &out[ob]);
      __builtin_nontemporal_store(hn[1], &out[ob + (size_t)1 * 512 * 1024]);
      __builtin_nontemporal_store(hn[2], &out[ob + (size_t)2 * 512 * 1024]);
      __builtin_nontemporal_store(hn[3], &out[ob + (size_t)3 * 512 * 1024]);
      if (t == 511) {
        const size_t fb = (size_t)(bg * 16 + quad * 4) * 1024 + ng * 16 + ml;
        __builtin_nontemporal_store(hn[0], &hfin[fb]);
        __builtin_nontemporal_store(hn[1], &hfin[fb + 1024]);
        __builtin_nontemporal_store(hn[2], &hfin[fb + 2048]);
        __builtin_nontemporal_store(hn[3], &hfin[fb + 3072]);
      }
    }
    spin_wait(peerflag, 2 * t + 2);

    // rotate prefetched xg regs
    if (wid == 0) {
      #pragma unroll
      for (int r = 0; r < 4; ++r) { xz_c[r] = xz_n[r]; xn_c[r] = xn_n[r]; }
    } else if (wid == 1) {
      #pragma unroll
      for (int r = 0; r < 4; ++r) xr_c[r] = xr_n[r];
    }
  }
}

// ---------------------------------------------------------------------------
extern "C" void kernel_launch(void* const* d_in, const int* in_sizes, int n_in,
                              void* d_out, int out_size, void* d_ws, size_t ws_size,
                              hipStream_t stream)
{
  const float* x  = (const float*)d_in[0];
  const float* Wi = (const float*)d_in[1];
  const float* bi = (const float*)d_in[2];
  const float* Wz = (const float*)d_in[3];
  const float* bz = (const float*)d_in[4];
  const float* Wr = (const float*)d_in[5];
  const float* br = (const float*)d_in[6];
  const float* Wn = (const float*)d_in[7];
  const float* bn = (const float*)d_in[8];
  float* out  = (float*)d_out;
  float* hfin = out + (size_t)64 * 512 * 1024;

  char* ws = (char*)d_ws;
  size_t off = 0;
  auto take = [&](size_t b) { size_t o = off; off += (b + 255) & ~(size_t)255; return o; };
  unsigned short* WhhT = (unsigned short*)(ws + take((size_t)3 * 1024 * 1024 * 2));
  unsigned short* WcT  = (unsigned short*)(ws + take((size_t)3072 * 256 * 2));
  float*          bc   = (float*)(ws + take(3072 * 4));
  unsigned short* hbuf = (unsigned short*)(ws + take((size_t)2 * 64 * 1024 * 2));
  unsigned short* rhb  = (unsigned short*)(ws + take((size_t)64 * 1024 * 2));
  int*            flags = (int*)(ws + take(256 * 32 * 4));
  const size_t xg_off = off;
  const bool xg_f32 = (ws_size >= xg_off + (size_t)32768 * 3072 * 4);
  void* xg = (void*)(ws + xg_off);

  hipMemsetAsync(hbuf, 0, (size_t)2 * 64 * 1024 * 2, stream);
  hipMemsetAsync(flags, 0, 256 * 32 * 4, stream);

  wc_kernel<<<768, 256, 0, stream>>>(Wi, Wz, Wr, Wn, WcT);
  bc_kernel<<<12, 256, 0, stream>>>(bi, Wz, Wr, Wn, bz, br, bn, bc);
  whT_kernel<<<768, 256, 0, stream>>>(Wz, Wr, Wn, WhhT);

  if (xg_f32) {
    gates_kernel<float><<<6144, 256, 0, stream>>>(x, WcT, bc, (float*)xg);
    const unsigned short* a0 = WhhT; const float* a1 = (const float*)xg;
    unsigned short* a2 = hbuf; unsigned short* a3 = rhb; int* a4 = flags;
    float* a5 = out; float* a6 = hfin;
    void* kargs[] = {&a0, &a1, &a2, &a3, &a4, &a5, &a6};
    hipError_t e = hipLaunchCooperativeKernel(
        reinterpret_cast<const void*>(&recur_kernel<float>),
        dim3(256), dim3(256), kargs, 0, stream);
    if (e != hipSuccess)
      recur_kernel<float><<<256, 256, 0, stream>>>(WhhT, (const float*)xg, hbuf, rhb, flags, out, hfin);
  } else {
    gates_kernel<unsigned short><<<6144, 256, 0, stream>>>(x, WcT, bc, (unsigned short*)xg);
    const unsigned short* a0 = WhhT; const unsigned short* a1 = (const unsigned short*)xg;
    unsigned short* a2 = hbuf; unsigned short* a3 = rhb; int* a4 = flags;
    float* a5 = out; float* a6 = hfin;
    void* kargs[] = {&a0, &a1, &a2, &a3, &a4, &a5, &a6};
    hipError_t e = hipLaunchCooperativeKernel(
        reinterpret_cast<const void*>(&recur_kernel<unsigned short>),
        dim3(256), dim3(256), kargs, 0, stream);
    if (e != hipSuccess)
      recur_kernel<unsigned short><<<256, 256, 0, stream>>>(WhhT, (const unsigned short*)xg, hbuf, rhb, flags, out, hfin);
  }
}